// Round 14
// baseline (133.165 us; speedup 1.0000x reference)
//
#include <hip/hip_runtime.h>
#include <hip/hip_bf16.h>
#include <stdint.h>

typedef short bf16x8 __attribute__((ext_vector_type(8)));
typedef float f32x4 __attribute__((ext_vector_type(4)));
typedef unsigned short u16;

#define GLOAD16(gp, lp)                                                        \
  __builtin_amdgcn_global_load_lds(                                            \
      (const __attribute__((address_space(1))) void*)(gp),                     \
      (__attribute__((address_space(3))) void*)(lp), 16, 0, 0)

__device__ __forceinline__ u16 f2bf(float f) {
  uint32_t u = __builtin_bit_cast(uint32_t, f);
  u = (u + 0x7FFFu + ((u >> 16) & 1u)) >> 16;
  return (u16)u;
}
__device__ __forceinline__ float bf2f(u16 v) {
  return __builtin_bit_cast(float, (uint32_t)v << 16);
}

// LDS pair-line swizzle: logical (row, 16B-unit u in 0..3) -> byte offset.
// Frag reads (16 rows, fixed u) hit each 16B slot exactly 2x => free.
__device__ __forceinline__ int swzoff(int row, int u) {
  int p = row >> 1;
  int us = ((row & 1) * 4 + u) ^ (p & 7);
  return p * 128 + us * 16;
}

// ================= mega pre-pass: packs + router + conv, ONE launch =========
__global__ void mega(const float* __restrict__ x, const float* __restrict__ rw,
                     const float* __restrict__ eg, const float* __restrict__ eu,
                     const float* __restrict__ ed, const float* __restrict__ sg,
                     const float* __restrict__ su, const float* __restrict__ sd,
                     u16* __restrict__ Xb, u16* __restrict__ WpT,
                     u16* __restrict__ Wd2, u16* __restrict__ Wds,
                     float4* __restrict__ meta) {
  __shared__ float t[64][65];
  const int tid = threadIdx.x;
  const int b = blockIdx.x;
  if (b < 1280) {
    const float* src; int k0, h0;
    const bool is_e = b < 1024;
    if (is_e) { src = ed; k0 = (b >> 4) * 64;          h0 = (b & 15) * 64; }
    else      { src = sd; k0 = ((b - 1024) >> 4) * 64; h0 = (b & 15) * 64; }
#pragma unroll
    for (int p = 0; p < 4; ++p) {
      int r = p * 16 + (tid >> 4), c = (tid & 15) * 4;
      float4 v = *(const float4*)&src[(size_t)(k0 + r) * 1024 + h0 + c];
      t[r][c] = v.x; t[r][c + 1] = v.y; t[r][c + 2] = v.z; t[r][c + 3] = v.w;
    }
    __syncthreads();
#pragma unroll
    for (int p = 0; p < 4; ++p) {
      int hl = p * 16 + (tid >> 4), kl = (tid & 15) * 4;
      ushort4 o;
      o.x = f2bf(t[kl][hl]);     o.y = f2bf(t[kl + 1][hl]);
      o.z = f2bf(t[kl + 2][hl]); o.w = f2bf(t[kl + 3][hl]);
      if (is_e) {
        int kk = k0 + kl;
        int e = kk >> 9, dk = kk & 511;
        *(ushort4*)&Wd2[(size_t)e * 524288 + (size_t)(h0 + hl) * 512 + dk] = o;
      } else {
        *(ushort4*)&Wds[(size_t)(h0 + hl) * 1024 + k0 + kl] = o;
      }
    }
  } else if (b < 3840) {
    int bb = b - 1280;
    const float* src; int pbase, C, dt, ht;
    if (bb < 2048) {
      int slice = bb >> 7, r = bb & 127;
      int e = slice >> 1; int up = slice & 1;
      src = (up ? eu : eg) + (size_t)e * 524288;
      pbase = e * 1024 + up * 32; C = 512;
      dt = r >> 4; ht = r & 15;
    } else {
      int r = bb - 2048;
      int up = r >= 256; r &= 255;
      src = up ? su : sg; pbase = 8192 + up * 32; C = 1024;
      dt = r >> 4; ht = r & 15;
    }
    const int d0 = dt * 64, h0 = ht * 64;
#pragma unroll
    for (int p = 0; p < 4; ++p) {
      int hl = p * 16 + (tid >> 4), dl = (tid & 15) * 4;
      float4 v = *(const float4*)&src[(size_t)(h0 + hl) * C + d0 + dl];
      t[hl][dl] = v.x; t[hl][dl + 1] = v.y; t[hl][dl + 2] = v.z; t[hl][dl + 3] = v.w;
    }
    __syncthreads();
#pragma unroll
    for (int p = 0; p < 4; ++p) {
      int dl = p * 16 + (tid >> 4), hl = (tid & 15) * 4;
      int d = d0 + dl;
      int prow = pbase + ((d >> 5) << 6) + (d & 31);
      ushort4 o;
      o.x = f2bf(t[hl][dl]);     o.y = f2bf(t[hl + 1][dl]);
      o.z = f2bf(t[hl + 2][dl]); o.w = f2bf(t[hl + 3][dl]);
      *(ushort4*)&WpT[(size_t)prow * 1024 + h0 + hl] = o;
    }
  } else if (b < 4864) {
    const int l = tid & 63;
    const int tok = (b - 3840) * 4 + (tid >> 6);
    const float* xr = x + (size_t)tok * 1024;
    float acc[8];
#pragma unroll
    for (int e = 0; e < 8; ++e) acc[e] = 0.f;
    for (int it = 0; it < 16; ++it) {
      int h = it * 64 + l;
      float xv = xr[h];
      float4 r0 = *(const float4*)&rw[h * 8];
      float4 r1 = *(const float4*)&rw[h * 8 + 4];
      acc[0] += xv * r0.x; acc[1] += xv * r0.y; acc[2] += xv * r0.z; acc[3] += xv * r0.w;
      acc[4] += xv * r1.x; acc[5] += xv * r1.y; acc[6] += xv * r1.z; acc[7] += xv * r1.w;
    }
#pragma unroll
    for (int off = 32; off >= 1; off >>= 1) {
#pragma unroll
      for (int e = 0; e < 8; ++e) acc[e] += __shfl_xor(acc[e], off, 64);
    }
    if (l == 0) {
      float m = acc[0];
#pragma unroll
      for (int e = 1; e < 8; ++e) m = fmaxf(m, acc[e]);
      float p[8], s = 0.f;
#pragma unroll
      for (int e = 0; e < 8; ++e) { p[e] = expf(acc[e] - m); s += p[e]; }
      int i1 = 0;
#pragma unroll
      for (int e = 1; e < 8; ++e) if (p[e] > p[i1]) i1 = e;
      int i2 = (i1 == 0) ? 1 : 0;
#pragma unroll
      for (int e = 0; e < 8; ++e) if (e != i1 && p[e] > p[i2]) i2 = e;
      float inv = 1.f / s;
      meta[tok] = make_float4(__int_as_float(i1), __int_as_float(i2),
                              p[i1] * inv, p[i2] * inv);
    }
  } else {
    int i = (b - 4864) * 512 + tid;
#pragma unroll
    for (int k = 0; k < 2; ++k) {
      float4 v = ((const float4*)x)[i + k * 256];
      ushort4 o;
      o.x = f2bf(v.x); o.y = f2bf(v.y); o.z = f2bf(v.z); o.w = f2bf(v.w);
      ((ushort4*)Xb)[i + k * 256] = o;
    }
  }
}

// ------- deterministic ballot-based compaction: 1 block, 8 waves = 8 experts
__global__ __launch_bounds__(512) void assign_k(const float4* __restrict__ meta,
                                                int* __restrict__ counts_g,
                                                int* __restrict__ list_tok,
                                                int2* __restrict__ t2s) {
  __shared__ u16 sel[4096];   // e1 | e2<<8
  __shared__ int cnt_s[8];
  const int tid = threadIdx.x;
  for (int i = tid; i < 4096; i += 512) {
    float4 m = meta[i];
    sel[i] = (u16)(__float_as_int(m.x) | (__float_as_int(m.y) << 8));
  }
  __syncthreads();

  const int E = tid >> 6;
  const int lane = tid & 63;
  const unsigned long long lt = (lane == 63) ? ~0ull >> 1 : ((1ull << lane) - 1ull);

  int total = 0;
#pragma unroll 8
  for (int it = 0; it < 64; ++it) {
    u16 s = sel[it * 64 + lane];
    bool any = ((s & 255) == E) || ((s >> 8) == E);
    total += __popcll(__ballot(any));
  }
  if (lane == 0) { cnt_s[E] = total; counts_g[E] = total; }
  __syncthreads();
  int base = 0;
#pragma unroll
  for (int e = 0; e < 8; ++e) base += (e < E) ? cnt_s[e] : 0;

  int running = base;
  for (int it = 0; it < 64; ++it) {
    int tok = it * 64 + lane;
    u16 s = sel[tok];
    bool s1 = ((s & 255) == E);
    bool s2 = ((s >> 8) == E);
    unsigned long long mask = __ballot(s1 || s2);
    int pos = running + __popcll(mask & lt);
    if (s1 || s2) {
      list_tok[pos] = tok;
      if (s1) t2s[tok].x = pos;
      else    t2s[tok].y = pos;
    }
    running += __popcll(mask);
  }
}

// ===== compacted-MoE GEMM: 128x256 block, FOUR waves of 64x128 each =========
// Wave intensity 0.375 ds_read/MFMA (vs 0.5 at 64x64) -> per-CU LDS/step
// 128->96 KB: matrix pipe becomes critical. 2 blocks/CU kept (144KB LDS).
// 3-slot ring + deep counted vmcnt (stage-to-use ~2 iters, never drains).
template <int MODE>
__global__ __launch_bounds__(256, 2) void moe_gemm(
    const u16* __restrict__ Xb, const u16* __restrict__ WpT,
    const u16* __restrict__ Wd2, const u16* __restrict__ Wds,
    u16* __restrict__ Hs, u16* __restrict__ Hcomp, u16* __restrict__ Pb,
    float* __restrict__ out,
    const int* __restrict__ counts, const int* __restrict__ list_tok) {
  constexpr int SLOT = (128 + 256) * 64;  // 24 KB
  constexpr int BOFF = 128 * 64;
  __shared__ __align__(16) char lds[3 * SLOT];  // 72 KB -> 2 blocks/CU

  const int tid = threadIdx.x;
  const int l = tid & 63, l15 = l & 15, lg = l >> 4;
  const int wv = tid >> 6, wr = wv >> 1, wc = wv & 1;  // 2M x 2N waves, 64x128

  const int id = blockIdx.x;
  const bool routed = id < 288;
  int expert = 0, m0 = 0, n0 = 0, base = 0, count = 0, nt;

  if (routed) {
    int mtf = id >> 2; n0 = (id & 3) * 256;
    int acc_ = 0, bas = 0, found = 0;
#pragma unroll
    for (int e = 0; e < 8; ++e) {
      int c = counts[e];
      int nm = (c + 127) >> 7;
      if (!found && mtf < acc_ + nm) {
        expert = e; m0 = (mtf - acc_) * 128; base = bas; count = c; found = 1;
      }
      acc_ += nm; bas += c;
    }
    if (!found) return;
  } else {
    // shared part: XCD-localized bijective mapping
    int sid = id - 288;
    int xcd = sid & 7, pos = sid >> 3;
    int mG = xcd >> 1, nG = xcd & 1;
    if (MODE == 0) {           // 32 m-tiles x 8 n-tiles, 256 blocks
      int mL = pos & 7, nL = pos >> 3;
      m0 = (mG * 8 + mL) * 128; n0 = (nG * 4 + nL) * 256;
    } else {                   // 32 m-tiles x 4 n-tiles, 128 blocks
      int mL = pos & 7, nL = pos >> 3;
      m0 = (mG * 8 + mL) * 128; n0 = (nG * 2 + nL) * 256;
    }
  }
  nt = (MODE == 1 && routed) ? 16 : 32;

  // ---- per-thread staging sources (pre-swizzled, rule #21); 256 threads ----
  const char* gA[2]; const char* gB[4]; int lA[2], lB[4];
#pragma unroll
  for (int j = 0; j < 2; ++j) {
    int L = (j * 256 + tid) * 16;
    int p = L >> 7, uph = (L >> 4) & 7;
    int usw = uph ^ (p & 7);
    int row = 2 * p + (usw >> 2), ulog = usw & 3;
    const u16* ap;
    if (MODE == 0) {
      if (routed) {
        int ar = min(m0 + row, count - 1);
        ap = Xb + (size_t)list_tok[base + ar] * 1024;
      } else ap = Xb + (size_t)(m0 + row) * 1024;
    } else {
      if (routed) ap = Hcomp + (size_t)(base + min(m0 + row, count - 1)) * 512;
      else        ap = Hs + (size_t)(m0 + row) * 1024;
    }
    gA[j] = (const char*)ap + ulog * 16;
    lA[j] = L;
  }
#pragma unroll
  for (int j = 0; j < 4; ++j) {
    int L = (j * 256 + tid) * 16;
    int p = L >> 7, uph = (L >> 4) & 7;
    int usw = uph ^ (p & 7);
    int row = 2 * p + (usw >> 2), ulog = usw & 3;
    const u16* bp;
    if (MODE == 0) {
      int rbase = routed ? expert * 1024 : 8192;
      bp = WpT + (size_t)(rbase + n0 + row) * 1024;
    } else {
      if (routed) bp = Wd2 + (size_t)expert * 524288 + (size_t)(n0 + row) * 512;
      else        bp = Wds + (size_t)(n0 + row) * 1024;
    }
    gB[j] = (const char*)bp + ulog * 16;
    lB[j] = L;
  }

  int offA[4], offB[8];
#pragma unroll
  for (int m = 0; m < 4; ++m) offA[m] = swzoff(wr * 64 + m * 16 + l15, lg);
#pragma unroll
  for (int n = 0; n < 8; ++n) offB[n] = BOFF + swzoff(wc * 128 + n * 16 + l15, lg);

  f32x4 acc[4][8];
#pragma unroll
  for (int m = 0; m < 4; ++m)
#pragma unroll
    for (int n = 0; n < 8; ++n) acc[m][n] = {0.f, 0.f, 0.f, 0.f};

#define STAGE(T)                                                               \
  {                                                                            \
    char* sb_ = lds + (((T) % 3) * SLOT);                                      \
    const int tb_ = (T) * 64;                                                  \
    GLOAD16(gA[0] + tb_, sb_ + lA[0]);                                         \
    GLOAD16(gA[1] + tb_, sb_ + lA[1]);                                         \
    GLOAD16(gB[0] + tb_, sb_ + BOFF + lB[0]);                                  \
    GLOAD16(gB[1] + tb_, sb_ + BOFF + lB[1]);                                  \
    GLOAD16(gB[2] + tb_, sb_ + BOFF + lB[2]);                                  \
    GLOAD16(gB[3] + tb_, sb_ + BOFF + lB[3]);                                  \
  }

  STAGE(0); STAGE(1);

  for (int t = 0; t < nt; ++t) {
    if (t + 1 < nt) {
      asm volatile("s_waitcnt vmcnt(6)" ::: "memory");  // slot t landed; t+1 flies
    } else {
      asm volatile("s_waitcnt vmcnt(0)" ::: "memory");
    }
    __builtin_amdgcn_s_barrier();                       // collective
    asm volatile("" ::: "memory");
    char* sb = lds + ((t % 3) * SLOT);
    bf16x8 af[4], bfr[8];
#pragma unroll
    for (int m = 0; m < 4; ++m) af[m] = *(const bf16x8*)(sb + offA[m]);
#pragma unroll
    for (int n = 0; n < 8; ++n) bfr[n] = *(const bf16x8*)(sb + offB[n]);
    if (t + 2 < nt) STAGE(t + 2);                       // overwrite slot t-1 (retired)
    __builtin_amdgcn_s_setprio(1);
#pragma unroll
    for (int m = 0; m < 4; ++m)
#pragma unroll
      for (int n = 0; n < 8; ++n)
        acc[m][n] = __builtin_amdgcn_mfma_f32_16x16x32_bf16(af[m], bfr[n], acc[m][n], 0, 0, 0);
    __builtin_amdgcn_s_setprio(0);
    asm volatile("" ::: "memory");
  }
#undef STAGE

  const int rbl = wr * 64 + lg * 4;
  const int cnt_lim = routed ? count : (1 << 30);
  if constexpr (MODE == 0) {
    // SwiGLU epilogue; wave spans TWO packed 64-blocks (32g+32u each)
    u16* dst = routed ? Hcomp : Hs;
    const int ldH = routed ? 512 : 1024;
    const int rowbase = routed ? (base + m0) : m0;
#pragma unroll
    for (int m = 0; m < 4; ++m)
#pragma unroll
      for (int blk = 0; blk < 2; ++blk)
#pragma unroll
        for (int q = 0; q < 2; ++q) {
          int cD = ((n0 + wc * 128 + blk * 64) >> 1) + q * 16 + l15;
#pragma unroll
          for (int j = 0; j < 4; ++j) {
            int mrow = rbl + m * 16 + j;
            if (m0 + mrow < cnt_lim) {
              float g = acc[m][blk * 4 + q][j];
              float u = acc[m][blk * 4 + q + 2][j];
              dst[(size_t)(rowbase + mrow) * ldH + cD] =
                  f2bf(g / (1.f + __expf(-g)) * u);
            }
          }
        }
  } else {
    const int cb = n0 + wc * 128;
#pragma unroll
    for (int m = 0; m < 4; ++m)
#pragma unroll
      for (int n = 0; n < 8; ++n)
#pragma unroll
        for (int j = 0; j < 4; ++j) {
          int mrow = rbl + m * 16 + j;
          if (m0 + mrow < cnt_lim) {
            int col = cb + n * 16 + l15;
            if (routed)
              Pb[(size_t)(base + m0 + mrow) * 1024 + col] = f2bf(acc[m][n][j]);
            else
              out[(size_t)(m0 + mrow) * 1024 + col] = acc[m][n][j];
          }
        }
  }
}

// ------ final combine: out[t] = shared_out[t] + p1*Pb[slotA] + p2*Pb[slotB] -
__global__ void reduce_k(const float4* __restrict__ meta, const int2* __restrict__ t2s,
                         const u16* __restrict__ Pb, float* __restrict__ out) {
  const int t = blockIdx.x;
  const int c = threadIdx.x * 4;
  float4 m = meta[t];
  int2 s = t2s[t];
  float p1 = m.z, p2 = m.w;
  ushort4 a = *(const ushort4*)&Pb[(size_t)s.x * 1024 + c];
  ushort4 bb = *(const ushort4*)&Pb[(size_t)s.y * 1024 + c];
  float4 o = *(float4*)&out[(size_t)t * 1024 + c];
  o.x += p1 * bf2f(a.x) + p2 * bf2f(bb.x);
  o.y += p1 * bf2f(a.y) + p2 * bf2f(bb.y);
  o.z += p1 * bf2f(a.z) + p2 * bf2f(bb.z);
  o.w += p1 * bf2f(a.w) + p2 * bf2f(bb.w);
  *(float4*)&out[(size_t)t * 1024 + c] = o;
}

extern "C" void kernel_launch(void* const* d_in, const int* in_sizes, int n_in,
                              void* d_out, int out_size, void* d_ws, size_t ws_size,
                              hipStream_t stream) {
  const float* x  = (const float*)d_in[0];
  const float* rw = (const float*)d_in[1];
  const float* eg = (const float*)d_in[2];
  const float* eu = (const float*)d_in[3];
  const float* ed = (const float*)d_in[4];
  const float* sg = (const float*)d_in[5];
  const float* su = (const float*)d_in[6];
  const float* sd = (const float*)d_in[7];
  float* out = (float*)d_out;

  char* ws = (char*)d_ws;
  u16*    Xb    = (u16*)(ws);                 // 8,388,608
  u16*    WpT   = (u16*)(ws + 8388608);       // 20,971,520
  u16*    Wd2   = (u16*)(ws + 29360128);      // 8,388,608  [8][1024][512] bf16
  u16*    Wds   = (u16*)(ws + 37748736);      // 2,097,152  [1024][1024] bf16
  u16*    Hs    = (u16*)(ws + 39845888);      // 8,388,608  [4096][1024] bf16
  u16*    Hcomp = (u16*)(ws + 48234496);      // 8,388,608  [8192][512] bf16
  u16*    Pb    = (u16*)(ws + 56623104);      // 16,777,216 [8192][1024] bf16
  float4* meta  = (float4*)(ws + 73400320);   // 65,536  (e1,e2,p1,p2)/token
  int2*   t2s   = (int2*)(ws + 73465856);     // 32,768
  int*    counts= (int*)(ws + 73498624);      // 32
  int*    list_tok = (int*)(ws + 73498688);   // 32,768

  mega<<<6912, 256, 0, stream>>>(x, rw, eg, eu, ed, sg, su, sd,
                                 Xb, WpT, Wd2, Wds, meta);
  assign_k<<<1, 512, 0, stream>>>(meta, counts, list_tok, t2s);

  // gate/up: routed (288 worst-case) + shared (256, XCD-localized)
  moe_gemm<0><<<544, 256, 0, stream>>>(Xb, WpT, Wd2, Wds, Hs, Hcomp, Pb, out,
                                       counts, list_tok);
  // down: routed (288) + shared (128, XCD-localized)
  moe_gemm<1><<<416, 256, 0, stream>>>(Xb, WpT, Wd2, Wds, Hs, Hcomp, Pb, out,
                                       counts, list_tok);

  reduce_k<<<4096, 256, 0, stream>>>(meta, t2s, Pb, out);
}

// Round 15
// 125.658 us; speedup vs baseline: 1.0597x; 1.0597x over previous
//
#include <hip/hip_runtime.h>
#include <hip/hip_bf16.h>
#include <stdint.h>

typedef short bf16x8 __attribute__((ext_vector_type(8)));
typedef float f32x4 __attribute__((ext_vector_type(4)));
typedef unsigned short u16;

#define GLOAD16(gp, lp)                                                        \
  __builtin_amdgcn_global_load_lds(                                            \
      (const __attribute__((address_space(1))) void*)(gp),                     \
      (__attribute__((address_space(3))) void*)(lp), 16, 0, 0)

__device__ __forceinline__ u16 f2bf(float f) {
  uint32_t u = __builtin_bit_cast(uint32_t, f);
  u = (u + 0x7FFFu + ((u >> 16) & 1u)) >> 16;
  return (u16)u;
}
__device__ __forceinline__ float bf2f(u16 v) {
  return __builtin_bit_cast(float, (uint32_t)v << 16);
}

// LDS pair-line swizzle: logical (row, 16B-unit u in 0..3) -> byte offset.
// Frag reads (16 rows, fixed u) hit each 16B slot exactly 2x => free.
__device__ __forceinline__ int swzoff(int row, int u) {
  int p = row >> 1;
  int us = ((row & 1) * 4 + u) ^ (p & 7);
  return p * 128 + us * 16;
}

// ================= mega pre-pass: packs + router + conv, ONE launch =========
__global__ void mega(const float* __restrict__ x, const float* __restrict__ rw,
                     const float* __restrict__ eg, const float* __restrict__ eu,
                     const float* __restrict__ ed, const float* __restrict__ sg,
                     const float* __restrict__ su, const float* __restrict__ sd,
                     u16* __restrict__ Xb, u16* __restrict__ WpT,
                     u16* __restrict__ Wd2, u16* __restrict__ Wds,
                     float4* __restrict__ meta) {
  __shared__ float t[64][65];
  const int tid = threadIdx.x;
  const int b = blockIdx.x;
  if (b < 1280) {
    const float* src; int k0, h0;
    const bool is_e = b < 1024;
    if (is_e) { src = ed; k0 = (b >> 4) * 64;          h0 = (b & 15) * 64; }
    else      { src = sd; k0 = ((b - 1024) >> 4) * 64; h0 = (b & 15) * 64; }
#pragma unroll
    for (int p = 0; p < 4; ++p) {
      int r = p * 16 + (tid >> 4), c = (tid & 15) * 4;
      float4 v = *(const float4*)&src[(size_t)(k0 + r) * 1024 + h0 + c];
      t[r][c] = v.x; t[r][c + 1] = v.y; t[r][c + 2] = v.z; t[r][c + 3] = v.w;
    }
    __syncthreads();
#pragma unroll
    for (int p = 0; p < 4; ++p) {
      int hl = p * 16 + (tid >> 4), kl = (tid & 15) * 4;
      ushort4 o;
      o.x = f2bf(t[kl][hl]);     o.y = f2bf(t[kl + 1][hl]);
      o.z = f2bf(t[kl + 2][hl]); o.w = f2bf(t[kl + 3][hl]);
      if (is_e) {
        int kk = k0 + kl;
        int e = kk >> 9, dk = kk & 511;
        *(ushort4*)&Wd2[(size_t)e * 524288 + (size_t)(h0 + hl) * 512 + dk] = o;
      } else {
        *(ushort4*)&Wds[(size_t)(h0 + hl) * 1024 + k0 + kl] = o;
      }
    }
  } else if (b < 3840) {
    int bb = b - 1280;
    const float* src; int pbase, C, dt, ht;
    if (bb < 2048) {
      int slice = bb >> 7, r = bb & 127;
      int e = slice >> 1; int up = slice & 1;
      src = (up ? eu : eg) + (size_t)e * 524288;
      pbase = e * 1024 + up * 32; C = 512;
      dt = r >> 4; ht = r & 15;
    } else {
      int r = bb - 2048;
      int up = r >= 256; r &= 255;
      src = up ? su : sg; pbase = 8192 + up * 32; C = 1024;
      dt = r >> 4; ht = r & 15;
    }
    const int d0 = dt * 64, h0 = ht * 64;
#pragma unroll
    for (int p = 0; p < 4; ++p) {
      int hl = p * 16 + (tid >> 4), dl = (tid & 15) * 4;
      float4 v = *(const float4*)&src[(size_t)(h0 + hl) * C + d0 + dl];
      t[hl][dl] = v.x; t[hl][dl + 1] = v.y; t[hl][dl + 2] = v.z; t[hl][dl + 3] = v.w;
    }
    __syncthreads();
#pragma unroll
    for (int p = 0; p < 4; ++p) {
      int dl = p * 16 + (tid >> 4), hl = (tid & 15) * 4;
      int d = d0 + dl;
      int prow = pbase + ((d >> 5) << 6) + (d & 31);
      ushort4 o;
      o.x = f2bf(t[hl][dl]);     o.y = f2bf(t[hl + 1][dl]);
      o.z = f2bf(t[hl + 2][dl]); o.w = f2bf(t[hl + 3][dl]);
      *(ushort4*)&WpT[(size_t)prow * 1024 + h0 + hl] = o;
    }
  } else if (b < 4864) {
    const int l = tid & 63;
    const int tok = (b - 3840) * 4 + (tid >> 6);
    const float* xr = x + (size_t)tok * 1024;
    float acc[8];
#pragma unroll
    for (int e = 0; e < 8; ++e) acc[e] = 0.f;
    for (int it = 0; it < 16; ++it) {
      int h = it * 64 + l;
      float xv = xr[h];
      float4 r0 = *(const float4*)&rw[h * 8];
      float4 r1 = *(const float4*)&rw[h * 8 + 4];
      acc[0] += xv * r0.x; acc[1] += xv * r0.y; acc[2] += xv * r0.z; acc[3] += xv * r0.w;
      acc[4] += xv * r1.x; acc[5] += xv * r1.y; acc[6] += xv * r1.z; acc[7] += xv * r1.w;
    }
#pragma unroll
    for (int off = 32; off >= 1; off >>= 1) {
#pragma unroll
      for (int e = 0; e < 8; ++e) acc[e] += __shfl_xor(acc[e], off, 64);
    }
    if (l == 0) {
      float m = acc[0];
#pragma unroll
      for (int e = 1; e < 8; ++e) m = fmaxf(m, acc[e]);
      float p[8], s = 0.f;
#pragma unroll
      for (int e = 0; e < 8; ++e) { p[e] = expf(acc[e] - m); s += p[e]; }
      int i1 = 0;
#pragma unroll
      for (int e = 1; e < 8; ++e) if (p[e] > p[i1]) i1 = e;
      int i2 = (i1 == 0) ? 1 : 0;
#pragma unroll
      for (int e = 0; e < 8; ++e) if (e != i1 && p[e] > p[i2]) i2 = e;
      float inv = 1.f / s;
      meta[tok] = make_float4(__int_as_float(i1), __int_as_float(i2),
                              p[i1] * inv, p[i2] * inv);
    }
  } else {
    int i = (b - 4864) * 512 + tid;
#pragma unroll
    for (int k = 0; k < 2; ++k) {
      float4 v = ((const float4*)x)[i + k * 256];
      ushort4 o;
      o.x = f2bf(v.x); o.y = f2bf(v.y); o.z = f2bf(v.z); o.w = f2bf(v.w);
      ((ushort4*)Xb)[i + k * 256] = o;
    }
  }
}

// ------- deterministic ballot-based compaction: 1 block, 8 waves = 8 experts
__global__ __launch_bounds__(512) void assign_k(const float4* __restrict__ meta,
                                                int* __restrict__ counts_g,
                                                int* __restrict__ list_tok,
                                                int2* __restrict__ t2s) {
  __shared__ u16 sel[4096];   // e1 | e2<<8
  __shared__ int cnt_s[8];
  const int tid = threadIdx.x;
  for (int i = tid; i < 4096; i += 512) {
    float4 m = meta[i];
    sel[i] = (u16)(__float_as_int(m.x) | (__float_as_int(m.y) << 8));
  }
  __syncthreads();

  const int E = tid >> 6;
  const int lane = tid & 63;
  const unsigned long long lt = (lane == 63) ? ~0ull >> 1 : ((1ull << lane) - 1ull);

  int total = 0;
#pragma unroll 8
  for (int it = 0; it < 64; ++it) {
    u16 s = sel[it * 64 + lane];
    bool any = ((s & 255) == E) || ((s >> 8) == E);
    total += __popcll(__ballot(any));
  }
  if (lane == 0) { cnt_s[E] = total; counts_g[E] = total; }
  __syncthreads();
  int base = 0;
#pragma unroll
  for (int e = 0; e < 8; ++e) base += (e < E) ? cnt_s[e] : 0;

  int running = base;
  for (int it = 0; it < 64; ++it) {
    int tok = it * 64 + lane;
    u16 s = sel[tok];
    bool s1 = ((s & 255) == E);
    bool s2 = ((s >> 8) == E);
    unsigned long long mask = __ballot(s1 || s2);
    int pos = running + __popcll(mask & lt);
    if (s1 || s2) {
      list_tok[pos] = tok;
      if (s1) t2s[tok].x = pos;
      else    t2s[tok].y = pos;
    }
    running += __popcll(mask);
  }
}

// ===== compacted-MoE GEMM: 128x256 block, 3-slot ring, deep counted vmcnt ===
// R13's measured-best structure. MODE 1 now UNIFORM nt=16: routed K=512,
// shared split-K (2 x 512) -> partials Ps0/Ps1 (merged in reduce_k).
template <int MODE>
__global__ __launch_bounds__(512, 2) void moe_gemm(
    const u16* __restrict__ Xb, const u16* __restrict__ WpT,
    const u16* __restrict__ Wd2, const u16* __restrict__ Wds,
    u16* __restrict__ Hs, u16* __restrict__ Hcomp, u16* __restrict__ Pb,
    u16* __restrict__ Ps0, u16* __restrict__ Ps1,
    const int* __restrict__ counts, const int* __restrict__ list_tok) {
  constexpr int SLOT = (128 + 256) * 64;  // 24 KB
  constexpr int BOFF = 128 * 64;
  __shared__ __align__(16) char lds[3 * SLOT];  // 72 KB -> 2 blocks/CU

  const int tid = threadIdx.x;
  const int l = tid & 63, l15 = l & 15, lg = l >> 4;
  const int wv = tid >> 6, wr = wv >> 2, wc = wv & 3;  // 2M x 4N waves

  const int id = blockIdx.x;
  const bool routed = id < 288;
  int expert = 0, m0 = 0, n0 = 0, base = 0, count = 0, nt, split = 0, kb = 0;

  if (routed) {
    int mtf = id >> 2; n0 = (id & 3) * 256;
    int acc_ = 0, bas = 0, found = 0;
#pragma unroll
    for (int e = 0; e < 8; ++e) {
      int c = counts[e];
      int nm = (c + 127) >> 7;
      if (!found && mtf < acc_ + nm) {
        expert = e; m0 = (mtf - acc_) * 128; base = bas; count = c; found = 1;
      }
      acc_ += nm; bas += c;
    }
    if (!found) return;
  } else {
    // shared part: XCD-localized bijective mapping
    int sid = id - 288;
    int xcd = sid & 7, pos = sid >> 3;
    int mG = xcd >> 1, nG = xcd & 1;
    if (MODE == 0) {           // 32 m-tiles x 8 n-tiles, 256 blocks
      int mL = pos & 7, nL = pos >> 3;
      m0 = (mG * 8 + mL) * 128; n0 = (nG * 4 + nL) * 256;
    } else {                   // 32 m x 4 n x 2 splits, 256 blocks
      split = pos & 1;
      int q = pos >> 1;        // 0..15
      int mL = q & 7, nL = q >> 3;
      m0 = (mG * 8 + mL) * 128; n0 = (nG * 2 + nL) * 256;
      kb = split * 512;
    }
  }
  nt = (MODE == 1) ? 16 : 32;

  // ---- per-thread staging sources (pre-swizzled, rule #21) ----
  const char* gA0; const char* gB[2]; int lA0, lB[2];
  {
    int L = tid * 16;
    int p = L >> 7, uph = (L >> 4) & 7;
    int usw = uph ^ (p & 7);
    int row = 2 * p + (usw >> 2), ulog = usw & 3;
    const u16* ap;
    if (MODE == 0) {
      if (routed) {
        int ar = min(m0 + row, count - 1);
        ap = Xb + (size_t)list_tok[base + ar] * 1024;
      } else ap = Xb + (size_t)(m0 + row) * 1024;
    } else {
      if (routed) ap = Hcomp + (size_t)(base + min(m0 + row, count - 1)) * 512;
      else        ap = Hs + (size_t)(m0 + row) * 1024 + kb;
    }
    gA0 = (const char*)ap + ulog * 16;
    lA0 = L;
  }
#pragma unroll
  for (int j = 0; j < 2; ++j) {
    int L = (j * 512 + tid) * 16;
    int p = L >> 7, uph = (L >> 4) & 7;
    int usw = uph ^ (p & 7);
    int row = 2 * p + (usw >> 2), ulog = usw & 3;
    const u16* bp;
    if (MODE == 0) {
      int rbase = routed ? expert * 1024 : 8192;
      bp = WpT + (size_t)(rbase + n0 + row) * 1024;
    } else {
      if (routed) bp = Wd2 + (size_t)expert * 524288 + (size_t)(n0 + row) * 512;
      else        bp = Wds + (size_t)(n0 + row) * 1024 + kb;
    }
    gB[j] = (const char*)bp + ulog * 16;
    lB[j] = L;
  }

  int offA[4], offB[4];
#pragma unroll
  for (int m = 0; m < 4; ++m) offA[m] = swzoff(wr * 64 + m * 16 + l15, lg);
#pragma unroll
  for (int n = 0; n < 4; ++n) offB[n] = BOFF + swzoff(wc * 64 + n * 16 + l15, lg);

  f32x4 acc[4][4];
#pragma unroll
  for (int m = 0; m < 4; ++m)
#pragma unroll
    for (int n = 0; n < 4; ++n) acc[m][n] = {0.f, 0.f, 0.f, 0.f};

#define STAGE(T)                                                               \
  {                                                                            \
    char* sb_ = lds + (((T) % 3) * SLOT);                                      \
    const int tb_ = (T) * 64;                                                  \
    GLOAD16(gA0 + tb_, sb_ + lA0);                                             \
    GLOAD16(gB[0] + tb_, sb_ + BOFF + lB[0]);                                  \
    GLOAD16(gB[1] + tb_, sb_ + BOFF + lB[1]);                                  \
  }

  STAGE(0); STAGE(1);

  for (int t = 0; t < nt; ++t) {
    if (t + 1 < nt) {
      asm volatile("s_waitcnt vmcnt(3)" ::: "memory");  // slot t landed; t+1 flies
    } else {
      asm volatile("s_waitcnt vmcnt(0)" ::: "memory");
    }
    __builtin_amdgcn_s_barrier();                       // collective
    asm volatile("" ::: "memory");
    char* sb = lds + ((t % 3) * SLOT);
    bf16x8 af[4], bfr[4];
#pragma unroll
    for (int m = 0; m < 4; ++m) af[m] = *(const bf16x8*)(sb + offA[m]);
#pragma unroll
    for (int n = 0; n < 4; ++n) bfr[n] = *(const bf16x8*)(sb + offB[n]);
    if (t + 2 < nt) STAGE(t + 2);                       // overwrite slot t-1 (retired)
    __builtin_amdgcn_s_setprio(1);
#pragma unroll
    for (int m = 0; m < 4; ++m)
#pragma unroll
      for (int n = 0; n < 4; ++n)
        acc[m][n] = __builtin_amdgcn_mfma_f32_16x16x32_bf16(af[m], bfr[n], acc[m][n], 0, 0, 0);
    __builtin_amdgcn_s_setprio(0);
    asm volatile("" ::: "memory");
  }
#undef STAGE

  const int rbl = wr * 64 + lg * 4;
  const int cnt_lim = routed ? count : (1 << 30);
  if constexpr (MODE == 0) {
    // SwiGLU epilogue (prob applied later at reduce); packed 64 = 32g + 32u
    u16* dst = routed ? Hcomp : Hs;
    const int ldH = routed ? 512 : 1024;
    const int rowbase = routed ? (base + m0) : m0;
    const int cD0 = (n0 + wc * 64) >> 1;
#pragma unroll
    for (int m = 0; m < 4; ++m)
#pragma unroll
      for (int q = 0; q < 2; ++q) {
        int cD = cD0 + q * 16 + l15;
#pragma unroll
        for (int j = 0; j < 4; ++j) {
          int mrow = rbl + m * 16 + j;
          if (m0 + mrow < cnt_lim) {
            float g = acc[m][q][j];
            float u = acc[m][q + 2][j];
            dst[(size_t)(rowbase + mrow) * ldH + cD] =
                f2bf(g / (1.f + __expf(-g)) * u);
          }
        }
      }
  } else {
    const int cb = n0 + wc * 64;
    u16* dstS = split ? Ps1 : Ps0;
#pragma unroll
    for (int m = 0; m < 4; ++m)
#pragma unroll
      for (int n = 0; n < 4; ++n)
#pragma unroll
        for (int j = 0; j < 4; ++j) {
          int mrow = rbl + m * 16 + j;
          if (m0 + mrow < cnt_lim) {
            int col = cb + n * 16 + l15;
            if (routed)
              Pb[(size_t)(base + m0 + mrow) * 1024 + col] = f2bf(acc[m][n][j]);
            else
              dstS[(size_t)(m0 + mrow) * 1024 + col] = f2bf(acc[m][n][j]);
          }
        }
  }
}

// -- final combine: out[t] = Ps0+Ps1 + p1*Pb[slotA] + p2*Pb[slotB] (pure write)
__global__ void reduce_k(const float4* __restrict__ meta, const int2* __restrict__ t2s,
                         const u16* __restrict__ Pb, const u16* __restrict__ Ps0,
                         const u16* __restrict__ Ps1, float* __restrict__ out) {
  const int t = blockIdx.x;
  const int c = threadIdx.x * 4;
  float4 m = meta[t];
  int2 s = t2s[t];
  float p1 = m.z, p2 = m.w;
  ushort4 a  = *(const ushort4*)&Pb[(size_t)s.x * 1024 + c];
  ushort4 bb = *(const ushort4*)&Pb[(size_t)s.y * 1024 + c];
  ushort4 u0 = *(const ushort4*)&Ps0[(size_t)t * 1024 + c];
  ushort4 u1 = *(const ushort4*)&Ps1[(size_t)t * 1024 + c];
  float4 o;
  o.x = bf2f(u0.x) + bf2f(u1.x) + p1 * bf2f(a.x) + p2 * bf2f(bb.x);
  o.y = bf2f(u0.y) + bf2f(u1.y) + p1 * bf2f(a.y) + p2 * bf2f(bb.y);
  o.z = bf2f(u0.z) + bf2f(u1.z) + p1 * bf2f(a.z) + p2 * bf2f(bb.z);
  o.w = bf2f(u0.w) + bf2f(u1.w) + p1 * bf2f(a.w) + p2 * bf2f(bb.w);
  *(float4*)&out[(size_t)t * 1024 + c] = o;
}

extern "C" void kernel_launch(void* const* d_in, const int* in_sizes, int n_in,
                              void* d_out, int out_size, void* d_ws, size_t ws_size,
                              hipStream_t stream) {
  const float* x  = (const float*)d_in[0];
  const float* rw = (const float*)d_in[1];
  const float* eg = (const float*)d_in[2];
  const float* eu = (const float*)d_in[3];
  const float* ed = (const float*)d_in[4];
  const float* sg = (const float*)d_in[5];
  const float* su = (const float*)d_in[6];
  const float* sd = (const float*)d_in[7];
  float* out = (float*)d_out;

  char* ws = (char*)d_ws;
  u16*    Xb    = (u16*)(ws);                 // 8,388,608
  u16*    WpT   = (u16*)(ws + 8388608);       // 20,971,520 (dead after gemm<0>)
  u16*    Ps0   = (u16*)(ws + 8388608);       // 8 MB overlay on WpT
  u16*    Ps1   = (u16*)(ws + 16777216);      // 8 MB overlay on WpT
  u16*    Wd2   = (u16*)(ws + 29360128);      // 8,388,608  [8][1024][512] bf16
  u16*    Wds   = (u16*)(ws + 37748736);      // 2,097,152  [1024][1024] bf16
  u16*    Hs    = (u16*)(ws + 39845888);      // 8,388,608  [4096][1024] bf16
  u16*    Hcomp = (u16*)(ws + 48234496);      // 8,388,608  [8192][512] bf16
  u16*    Pb    = (u16*)(ws + 56623104);      // 16,777,216 [8192][1024] bf16
  float4* meta  = (float4*)(ws + 73400320);   // 65,536  (e1,e2,p1,p2)/token
  int2*   t2s   = (int2*)(ws + 73465856);     // 32,768
  int*    counts= (int*)(ws + 73498624);      // 32
  int*    list_tok = (int*)(ws + 73498688);   // 32,768

  mega<<<6912, 256, 0, stream>>>(x, rw, eg, eu, ed, sg, su, sd,
                                 Xb, WpT, Wd2, Wds, meta);
  assign_k<<<1, 512, 0, stream>>>(meta, counts, list_tok, t2s);

  // gate/up: routed (288 worst-case) + shared (256, XCD-localized)
  moe_gemm<0><<<544, 512, 0, stream>>>(Xb, WpT, Wd2, Wds, Hs, Hcomp, Pb,
                                       Ps0, Ps1, counts, list_tok);
  // down: routed (288, K=512) + shared (256, split-K 2x512) — ALL nt=16
  moe_gemm<1><<<544, 512, 0, stream>>>(Xb, WpT, Wd2, Wds, Hs, Hcomp, Pb,
                                       Ps0, Ps1, counts, list_tok);

  reduce_k<<<4096, 256, 0, stream>>>(meta, t2s, Pb, Ps0, Ps1, out);
}